// Round 1
// baseline (2877.832 us; speedup 1.0000x reference)
//
#include <hip/hip_runtime.h>
#include <stdint.h>

// ---------------- types ----------------
typedef unsigned short u16;
typedef __attribute__((ext_vector_type(8))) short  bf16x8;   // 8 bf16 = 4 VGPR (MFMA A/B frag)
typedef __attribute__((ext_vector_type(8))) u16    u16x8;
typedef __attribute__((ext_vector_type(4))) float  f32x4;

#define MFMA_BF16(a, b, c) __builtin_amdgcn_mfma_f32_16x16x32_bf16((a), (b), (c), 0, 0, 0)

// ---------------- problem constants ----------------
#define BATCH   2048
#define HID     256
#define GATES   1024          // 4*HID
#define INP     512
#define FSTEPS  32
#define RSTEPS  3
#define NFRAMES 34            // frames 30..63 packed

static constexpr size_t SZH = (size_t)BATCH * HID;     // elements in one h/c buffer

// ---------------- ws layout (bytes) ----------------
static constexpr size_t OFF_CTL = 0;                               // 256 B barrier ctl (zeroed)
static constexpr size_t OFF_C0F = 256;                             // 4 c buffers, fp32 (zeroed)
static constexpr size_t OFF_C1F = OFF_C0F + SZH * 4;
static constexpr size_t OFF_C0R = OFF_C1F + SZH * 4;
static constexpr size_t OFF_C1R = OFF_C0R + SZH * 4;
static constexpr size_t OFF_H0F = OFF_C1R + SZH * 4;               // 4 h buffers x 2 parities, bf16 (zeroed)
static constexpr size_t OFF_H1F = OFF_H0F + SZH * 4;               // each h buf = 2*SZH u16 = SZH*4 bytes
static constexpr size_t OFF_H0R = OFF_H1F + SZH * 4;
static constexpr size_t OFF_H1R = OFF_H0R + SZH * 4;
static constexpr size_t ZERO_BYTES = OFF_H1R + SZH * 4;            // ~16.8 MB zeroed per launch
static constexpr size_t OFF_LAT = ZERO_BYTES;                      // latent (2048,512) fp32
static constexpr size_t OFF_XBF = OFF_LAT + (size_t)BATCH * 512 * 4;
static constexpr size_t OFF_W0F = OFF_XBF + (size_t)NFRAMES * BATCH * INP * 2;
static constexpr size_t OFF_W1F = OFF_W0F + (size_t)GATES * 768 * 2;
static constexpr size_t OFF_W0R = OFF_W1F + (size_t)GATES * 512 * 2;
static constexpr size_t OFF_W1R = OFF_W0R + (size_t)GATES * 768 * 2;
static constexpr size_t OFF_B0F = OFF_W1R + (size_t)GATES * 512 * 2;
static constexpr size_t OFF_B1F = OFF_B0F + 4096;
static constexpr size_t OFF_B0R = OFF_B1F + 4096;
static constexpr size_t OFF_B1R = OFF_B0R + 4096;
static constexpr size_t WS_NEED = OFF_B1R + 4096;

// ---------------- small helpers ----------------
__device__ __forceinline__ u16 f2bf(float f) {           // RNE f32 -> bf16 bits
    unsigned u = __float_as_uint(f);
    unsigned r = (u + 0x7fffu + ((u >> 16) & 1u)) >> 16;
    return (u16)r;
}
__device__ __forceinline__ float sigm(float x) { return 1.0f / (1.0f + __expf(-x)); }
__device__ __forceinline__ float tanh_fast(float x) {
    float a = fabsf(x);
    float e = __expf(-2.0f * a);
    float t = (1.0f - e) / (1.0f + e);
    return x < 0.0f ? -t : t;
}

// device-scope sense barrier. ctl[0]=cnt, ctl[1]=gen, zeroed at launch.
__device__ __forceinline__ void gbar(unsigned* cnt, unsigned* gen, unsigned nwg) {
    __syncthreads();
    if (threadIdx.x == 0) {
        __threadfence();  // release: make this WG's phase writes visible device-wide
        unsigned g = __hip_atomic_fetch_add(gen, 0u, __ATOMIC_RELAXED, __HIP_MEMORY_SCOPE_AGENT);
        unsigned a = __hip_atomic_fetch_add(cnt, 1u, __ATOMIC_RELAXED, __HIP_MEMORY_SCOPE_AGENT);
        if (a == nwg - 1u) {
            __hip_atomic_store(cnt, 0u, __ATOMIC_RELAXED, __HIP_MEMORY_SCOPE_AGENT);
            __threadfence();
            __hip_atomic_store(gen, g + 1u, __ATOMIC_RELAXED, __HIP_MEMORY_SCOPE_AGENT);
        } else {
            while (__hip_atomic_fetch_add(gen, 0u, __ATOMIC_RELAXED, __HIP_MEMORY_SCOPE_AGENT) == g) {
                __builtin_amdgcn_s_sleep(2);
            }
        }
        __threadfence();  // acquire: invalidate stale lines before next phase reads
    }
    __syncthreads();
}

// ---------------- one LSTM layer-step phase ----------------
// gates(BATCH x GATES) = [src0 | src1] @ W^T (+bias); then LSTM cell update.
// WG tile: 128 rows x 16 h-cols (i.e. 4 gate col-blocks of 16, at hc, 256+hc, 512+hc, 768+hc).
// LDS: As[128][64] bf16 (16KB) + Bs[64][64] bf16 (8KB), XOR-swizzled (byte ^= (row&7)<<4).
__device__ __forceinline__ void lstm_phase(
    const u16* __restrict__ src0, int s0stride, int s0chunks,
    const u16* __restrict__ src1,                 // stride 256 (h buffer)
    int nchunks,                                  // K/64
    const u16* __restrict__ Wp, int wstride,      // packed [Wih|Whh] row-major (GATES x K) bf16
    const float* __restrict__ bias,               // bih+bhh, len 1024, fp32
    float* __restrict__ cbuf,                     // (BATCH x HID) fp32, owned per (row,hc)
    u16* __restrict__ hout,                       // (BATCH x HID) bf16, current parity
    float* __restrict__ latent_out,               // nullptr, or latent + dir*256 (row stride 512)
    char* lds)
{
    const int tid  = threadIdx.x;
    const int wv   = tid >> 6;
    const int lane = tid & 63;
    const int M0   = (blockIdx.x >> 4) * 128;
    const int HC0  = (blockIdx.x & 15) * 16;
    char* As = lds;           // [128][64] bf16 swizzled
    char* Bs = lds + 16384;   // [64][64]  bf16 swizzled

    f32x4 acc[4][2];
#pragma unroll
    for (int g = 0; g < 4; ++g)
#pragma unroll
        for (int m = 0; m < 2; ++m) acc[g][m] = (f32x4){0.f, 0.f, 0.f, 0.f};

    for (int kt = 0; kt < nchunks; ++kt) {
        // ---- stage A: 128 rows x 64 k (1024 16B-units, 4 per thread) ----
        const u16* sA; int str; int kin;
        if (kt < s0chunks) { sA = src0; str = s0stride; kin = kt * 64; }
        else               { sA = src1; str = 256;      kin = (kt - s0chunks) * 64; }
#pragma unroll
        for (int it = 0; it < 4; ++it) {
            int u = tid + it * 256;
            int row = u >> 3, c8 = (u & 7) << 3;
            u16x8 v = *(const u16x8*)(sA + (size_t)(M0 + row) * str + kin + c8);
            int byte = (row << 7) + (c8 << 1);
            byte ^= (row & 7) << 4;
            *(u16x8*)(As + byte) = v;
        }
        // ---- stage B: 64 selected gate rows x 64 k (512 units, 2 per thread) ----
#pragma unroll
        for (int it = 0; it < 2; ++it) {
            int u = tid + it * 256;
            int ns = u >> 3, c8 = (u & 7) << 3;
            int n = ((ns >> 4) << 8) + HC0 + (ns & 15);   // gate (ns>>4), h-col HC0+(ns&15)
            u16x8 v = *(const u16x8*)(Wp + (size_t)n * wstride + kt * 64 + c8);
            int byte = (ns << 7) + (c8 << 1);
            byte ^= (ns & 7) << 4;
            *(u16x8*)(Bs + byte) = v;
        }
        __syncthreads();
        // ---- compute: 2 k-subchunks of 32 ----
#pragma unroll
        for (int kk = 0; kk < 2; ++kk) {
            bf16x8 af[2];
#pragma unroll
            for (int m = 0; m < 2; ++m) {
                int row  = wv * 32 + m * 16 + (lane & 15);
                int kidx = kk * 32 + (lane >> 4) * 8;
                int byte = (row << 7) + (kidx << 1);
                byte ^= (row & 7) << 4;
                af[m] = *(const bf16x8*)(As + byte);
            }
#pragma unroll
            for (int g = 0; g < 4; ++g) {
                int ns   = g * 16 + (lane & 15);
                int kidx = kk * 32 + (lane >> 4) * 8;
                int byte = (ns << 7) + (kidx << 1);
                byte ^= (ns & 7) << 4;
                bf16x8 bfr = *(const bf16x8*)(Bs + byte);
                acc[g][0] = MFMA_BF16(af[0], bfr, acc[g][0]);
                acc[g][1] = MFMA_BF16(af[1], bfr, acc[g][1]);
            }
        }
        __syncthreads();
    }

    // ---- epilogue: per-lane LSTM cell. C/D frag: col=lane&15, row=(lane>>4)*4+r ----
    const int hc = HC0 + (lane & 15);
    const float bi = bias[hc], bf_ = bias[256 + hc], bg = bias[512 + hc], bo = bias[768 + hc];
#pragma unroll
    for (int m = 0; m < 2; ++m) {
#pragma unroll
        for (int r = 0; r < 4; ++r) {
            int row = M0 + wv * 32 + m * 16 + ((lane >> 4) << 2) + r;
            float gi = acc[0][m][r] + bi;
            float gf = acc[1][m][r] + bf_;
            float gg = acc[2][m][r] + bg;
            float go = acc[3][m][r] + bo;
            size_t ci = (size_t)row * HID + hc;
            float c_old = cbuf[ci];
            float cn = sigm(gf) * c_old + sigm(gi) * tanh_fast(gg);
            float hn = sigm(go) * tanh_fast(cn);
            cbuf[ci] = cn;
            hout[ci] = f2bf(hn);
            if (latent_out) latent_out[(size_t)row * 512 + hc] = hn;
        }
    }
}

// ---------------- persistent sequence kernel (grid = 256 WGs x 256 thr, 1/CU) ----------------
__global__ void __launch_bounds__(256)
lstm_persistent(const u16* __restrict__ xbf,
                const u16* __restrict__ W0f, const u16* __restrict__ W1f,
                const u16* __restrict__ W0r, const u16* __restrict__ W1r,
                const float* __restrict__ b0f, const float* __restrict__ b1f,
                const float* __restrict__ b0r, const float* __restrict__ b1r,
                u16* __restrict__ h0f, u16* __restrict__ h1f,
                u16* __restrict__ h0r, u16* __restrict__ h1r,
                float* __restrict__ c0f, float* __restrict__ c1f,
                float* __restrict__ c0r, float* __restrict__ c1r,
                float* __restrict__ latent, unsigned* __restrict__ ctl)
{
    __shared__ char lds[24576];
    unsigned* cnt = ctl;
    unsigned* gen = ctl + 1;
    const unsigned nwg = gridDim.x;

    for (int dir = 0; dir < 2; ++dir) {
        const int nst = dir ? RSTEPS : FSTEPS;
        const u16* W0 = dir ? W0r : W0f;
        const u16* W1 = dir ? W1r : W1f;
        const float* bb0 = dir ? b0r : b0f;
        const float* bb1 = dir ? b1r : b1f;
        u16* h0 = dir ? h0r : h0f;
        u16* h1 = dir ? h1r : h1f;
        float* cc0 = dir ? c0r : c0f;
        float* cc1 = dir ? c1r : c1f;
        float* latbase = latent + dir * 256;
        for (int t = 0; t < nst; ++t) {
            // frame index in packed x: fwd t -> t; rev t -> 33-t (frames 63,62,61)
            const u16* xsrc = xbf + (size_t)(dir ? (33 - t) : t) * ((size_t)BATCH * INP);
            // layer0: A=[x(512) | h0_prev(256)], K=768
            lstm_phase(xsrc, INP, 8,
                       h0 + ((t + 1) & 1) * SZH, 12,
                       W0, 768, bb0, cc0,
                       h0 + (t & 1) * SZH, nullptr, lds);
            gbar(cnt, gen, nwg);
            // layer1: A=[h0_cur(256) | h1_prev(256)], K=512
            lstm_phase(h0 + (t & 1) * SZH, HID, 4,
                       h1 + ((t + 1) & 1) * SZH, 8,
                       W1, 512, bb1, cc1,
                       h1 + (t & 1) * SZH,
                       (t == nst - 1) ? latbase : nullptr, lds);
            gbar(cnt, gen, nwg);
        }
    }
}

// ---------------- prep kernels ----------------
// pack [Wih | Whh] -> bf16 row-major (1024 x (di+256)); bias sum fp32
__global__ void pack_w_kernel(const float* __restrict__ Wih, const float* __restrict__ Whh,
                              const float* __restrict__ bih, const float* __restrict__ bhh,
                              int di, u16* __restrict__ Wout, float* __restrict__ bout)
{
    int K = di + 256;
    int total = GATES * K;
    int gt = blockIdx.x * blockDim.x + threadIdx.x;
    int stride = gridDim.x * blockDim.x;
    for (int i = gt; i < total; i += stride) {
        int n = i / K, k = i - n * K;
        float v = (k < di) ? Wih[(size_t)n * di + k] : Whh[(size_t)n * 256 + (k - di)];
        Wout[i] = f2bf(v);
    }
    if (gt < GATES) bout[gt] = bih[gt] + bhh[gt];
}

// pack xs frames 30..63 -> bf16 [f][b][512]
__global__ void pack_x_kernel(const float* __restrict__ xs, u16* __restrict__ xbf)
{
    const size_t total = (size_t)NFRAMES * BATCH * INP / 8;   // 16B units
    for (size_t u = (size_t)blockIdx.x * blockDim.x + threadIdx.x; u < total;
         u += (size_t)gridDim.x * blockDim.x) {
        size_t k8 = (u & 63) << 3;
        size_t bb = (u >> 6) & (BATCH - 1);
        size_t f  = u >> 17;                                  // 2^17 units per frame
        const float* s = xs + (bb * 64 + 30 + f) * 512 + k8;
        float4 v0 = *(const float4*)s;
        float4 v1 = *(const float4*)(s + 4);
        u16x8 o;
        o[0] = f2bf(v0.x); o[1] = f2bf(v0.y); o[2] = f2bf(v0.z); o[3] = f2bf(v0.w);
        o[4] = f2bf(v1.x); o[5] = f2bf(v1.y); o[6] = f2bf(v1.z); o[7] = f2bf(v1.w);
        *(u16x8*)(xbf + (u << 3)) = o;
    }
}

// out(2048 x 10) = latent(2048 x 512) @ W3^T + b3, all fp32
__global__ void final_linear(const float* __restrict__ latent, const float* __restrict__ W3,
                             const float* __restrict__ b3, float* __restrict__ out)
{
    int idx = blockIdx.x * blockDim.x + threadIdx.x;
    if (idx >= BATCH * 10) return;
    int bb = idx / 10, c = idx - bb * 10;
    const float* lrow = latent + (size_t)bb * 512;
    const float* wrow = W3 + (size_t)c * 512;
    float s = b3[c];
#pragma unroll 4
    for (int k = 0; k < 512; k += 4) {
        float4 lv = *(const float4*)(lrow + k);
        float4 wv = *(const float4*)(wrow + k);
        s += lv.x * wv.x + lv.y * wv.y + lv.z * wv.z + lv.w * wv.w;
    }
    out[idx] = s;
}

// ---------------- launch ----------------
extern "C" void kernel_launch(void* const* d_in, const int* in_sizes, int n_in,
                              void* d_out, int out_size, void* d_ws, size_t ws_size,
                              hipStream_t stream)
{
    (void)in_sizes; (void)n_in; (void)out_size;
    if (ws_size < WS_NEED) return;   // leaves d_out poisoned -> diagnosable as ws shortfall

    const float* xs     = (const float*)d_in[0];
    const float* Wih_f0 = (const float*)d_in[1];
    const float* Whh_f0 = (const float*)d_in[2];
    const float* bih_f0 = (const float*)d_in[3];
    const float* bhh_f0 = (const float*)d_in[4];
    const float* Wih_f1 = (const float*)d_in[5];
    const float* Whh_f1 = (const float*)d_in[6];
    const float* bih_f1 = (const float*)d_in[7];
    const float* bhh_f1 = (const float*)d_in[8];
    const float* Wih_r0 = (const float*)d_in[9];
    const float* Whh_r0 = (const float*)d_in[10];
    const float* bih_r0 = (const float*)d_in[11];
    const float* bhh_r0 = (const float*)d_in[12];
    const float* Wih_r1 = (const float*)d_in[13];
    const float* Whh_r1 = (const float*)d_in[14];
    const float* bih_r1 = (const float*)d_in[15];
    const float* bhh_r1 = (const float*)d_in[16];
    const float* W3     = (const float*)d_in[17];
    const float* b3     = (const float*)d_in[18];

    char* ws = (char*)d_ws;
    unsigned* ctl = (unsigned*)(ws + OFF_CTL);
    float* c0f = (float*)(ws + OFF_C0F);
    float* c1f = (float*)(ws + OFF_C1F);
    float* c0r = (float*)(ws + OFF_C0R);
    float* c1r = (float*)(ws + OFF_C1R);
    u16* h0f = (u16*)(ws + OFF_H0F);
    u16* h1f = (u16*)(ws + OFF_H1F);
    u16* h0r = (u16*)(ws + OFF_H0R);
    u16* h1r = (u16*)(ws + OFF_H1R);
    float* latent = (float*)(ws + OFF_LAT);
    u16* xbf = (u16*)(ws + OFF_XBF);
    u16* W0f = (u16*)(ws + OFF_W0F);
    u16* W1f = (u16*)(ws + OFF_W1F);
    u16* W0r = (u16*)(ws + OFF_W0R);
    u16* W1r = (u16*)(ws + OFF_W1R);
    float* b0f = (float*)(ws + OFF_B0F);
    float* b1f = (float*)(ws + OFF_B1F);
    float* b0r = (float*)(ws + OFF_B0R);
    float* b1r = (float*)(ws + OFF_B1R);

    // zero barrier ctl + c states + h parity buffers (captured in graph, re-runs every replay)
    hipMemsetAsync(d_ws, 0, ZERO_BYTES, stream);

    pack_w_kernel<<<64, 256, 0, stream>>>(Wih_f0, Whh_f0, bih_f0, bhh_f0, 512, W0f, b0f);
    pack_w_kernel<<<64, 256, 0, stream>>>(Wih_f1, Whh_f1, bih_f1, bhh_f1, 256, W1f, b1f);
    pack_w_kernel<<<64, 256, 0, stream>>>(Wih_r0, Whh_r0, bih_r0, bhh_r0, 512, W0r, b0r);
    pack_w_kernel<<<64, 256, 0, stream>>>(Wih_r1, Whh_r1, bih_r1, bhh_r1, 256, W1r, b1r);
    pack_x_kernel<<<2048, 256, 0, stream>>>(xs, xbf);

    lstm_persistent<<<256, 256, 0, stream>>>(xbf, W0f, W1f, W0r, W1r,
                                             b0f, b1f, b0r, b1r,
                                             h0f, h1f, h0r, h1r,
                                             c0f, c1f, c0r, c1r,
                                             latent, ctl);

    final_linear<<<80, 256, 0, stream>>>(latent, W3, b3, (float*)d_out);
}

// Round 2
// 1269.828 us; speedup vs baseline: 2.2663x; 2.2663x over previous
//
#include <hip/hip_runtime.h>
#include <stdint.h>

// ---------------- types ----------------
typedef unsigned short u16;
typedef __attribute__((ext_vector_type(8))) short  bf16x8;   // 8 bf16 (MFMA A/B frag)
typedef __attribute__((ext_vector_type(8))) u16    u16x8;
typedef __attribute__((ext_vector_type(4))) float  f32x4;

#define MFMA_BF16(a,b,c) __builtin_amdgcn_mfma_f32_16x16x32_bf16((a),(b),(c),0,0,0)

// ---------------- problem constants ----------------
#define BATCH   2048
#define HID     256
#define INP     512
#define FSTEPS  32
#define RSTEPS  3
#define NVF     35            // 32 fwd virtual frames + 3 rev

static constexpr size_t SZH  = (size_t)BATCH * HID;      // 524288 elements
static constexpr size_t HBUF = SZH * 2 * 2;              // 2 parities, bf16 -> 2 MiB

// ---------------- ws layout (bytes) ----------------
static constexpr size_t OFF_CTL = 0;                     // 16 groups x 256 B
static constexpr size_t OFF_H0F = 4096;
static constexpr size_t OFF_H1F = OFF_H0F + HBUF;
static constexpr size_t OFF_H0R = OFF_H1F + HBUF;
static constexpr size_t OFF_H1R = OFF_H0R + HBUF;
static constexpr size_t ZERO_BYTES = OFF_H1R + HBUF;     // ~8.4 MB zeroed per launch
static constexpr size_t OFF_LAT  = ZERO_BYTES;                         // latent fp32 (2048x512)
static constexpr size_t OFF_XP   = OFF_LAT + (size_t)BATCH * 512 * 4;  // xproj fp16 [35][2048][1024]
static constexpr size_t XP_BYTES = (size_t)NVF * BATCH * 1024 * 2;
static constexpr size_t OFF_W0XF = OFF_XP + XP_BYTES;                  // Wih0 fwd bf16 [1024][512]
static constexpr size_t OFF_W0XR = OFF_W0XF + (size_t)1024 * 512 * 2;
static constexpr size_t OFF_WH0F = OFF_W0XR + (size_t)1024 * 512 * 2;  // Whh0 bf16 [1024][256]
static constexpr size_t OFF_WH0R = OFF_WH0F + (size_t)1024 * 256 * 2;
static constexpr size_t OFF_W1F  = OFF_WH0R + (size_t)1024 * 256 * 2;  // [Wih1|Whh1] bf16 [1024][512]
static constexpr size_t OFF_W1R  = OFF_W1F + (size_t)1024 * 512 * 2;
static constexpr size_t OFF_BS0F = OFF_W1R + (size_t)1024 * 512 * 2;   // bih+bhh fp32 [1024] each
static constexpr size_t OFF_BS0R = OFF_BS0F + 4096;
static constexpr size_t OFF_BS1F = OFF_BS0R + 4096;
static constexpr size_t OFF_BS1R = OFF_BS1F + 4096;
static constexpr size_t WS_NEED  = OFF_BS1R + 4096;      // ~157 MB

// ---------------- small helpers ----------------
__device__ __forceinline__ u16 f2bf(float f) {           // RNE f32 -> bf16 bits
    unsigned u = __float_as_uint(f);
    unsigned r = (u + 0x7fffu + ((u >> 16) & 1u)) >> 16;
    return (u16)r;
}
__device__ __forceinline__ float sigm(float x) { return 1.0f / (1.0f + __expf(-x)); }
__device__ __forceinline__ float tanh_fast(float x) {
    float a = fabsf(x);
    float e = __expf(-2.0f * a);
    float t = (1.0f - e) / (1.0f + e);
    return x < 0.0f ? -t : t;
}

// 16-WG group sense barrier; c[0]=cnt, c[1]=gen (zeroed at launch). Poll via LOADS.
__device__ __forceinline__ void gbar16(unsigned* c) {
    __syncthreads();
    if (threadIdx.x == 0) {
        __threadfence();   // release: h writes visible device-wide
        unsigned g = __hip_atomic_load(c + 1, __ATOMIC_RELAXED, __HIP_MEMORY_SCOPE_AGENT);
        unsigned a = __hip_atomic_fetch_add(c, 1u, __ATOMIC_RELAXED, __HIP_MEMORY_SCOPE_AGENT);
        if (a == 15u) {
            __hip_atomic_store(c, 0u, __ATOMIC_RELAXED, __HIP_MEMORY_SCOPE_AGENT);
            __threadfence();
            __hip_atomic_store(c + 1, g + 1u, __ATOMIC_RELAXED, __HIP_MEMORY_SCOPE_AGENT);
        } else {
            while (__hip_atomic_load(c + 1, __ATOMIC_RELAXED, __HIP_MEMORY_SCOPE_AGENT) == g)
                __builtin_amdgcn_s_sleep(2);
        }
        __threadfence();   // acquire
    }
    __syncthreads();
}

// ---------------- sequential-kernel building blocks ----------------
struct Regs4 { u16x8 v[4]; };

__device__ __forceinline__ const u16* abase(const u16* s0, const u16* s1, int c) {
    return (c < 4) ? (s0 + c * 64) : (s1 + (c - 4) * 64);
}
__device__ __forceinline__ void load_A(Regs4& R, const u16* base, int M0, int tid) {
#pragma unroll
    for (int i = 0; i < 4; ++i) {
        int u = tid + i * 256;
        int row = u >> 3, c8 = (u & 7) << 3;
        R.v[i] = *(const u16x8*)(base + (size_t)(M0 + row) * HID + c8);
    }
}
__device__ __forceinline__ void write_A(char* buf, const Regs4& R, int tid) {
#pragma unroll
    for (int i = 0; i < 4; ++i) {
        int u = tid + i * 256;
        int row = u >> 3, c8 = (u & 7) << 3;
        int byte = (row << 7) + (c8 << 1);
        byte ^= (row & 7) << 4;
        *(u16x8*)(buf + byte) = R.v[i];
    }
}
__device__ __forceinline__ void compute_chunk(const char* Abuf, const char* W, int wklog,
                                              int kbase, int wv, int lane, f32x4 acc[4][2]) {
#pragma unroll
    for (int kk = 0; kk < 2; ++kk) {
        int kin = kk * 32 + (lane >> 4) * 8;
        bf16x8 a0, a1;
        {
            int row = wv * 32 + (lane & 15);
            int byte = (row << 7) + (kin << 1); byte ^= (row & 7) << 4;
            a0 = *(const bf16x8*)(Abuf + byte);
            int row1 = row + 16;
            byte = (row1 << 7) + (kin << 1); byte ^= (row1 & 7) << 4;
            a1 = *(const bf16x8*)(Abuf + byte);
        }
        int kg = kbase + kin;
#pragma unroll
        for (int g = 0; g < 4; ++g) {
            int ns = g * 16 + (lane & 15);
            int byte = (ns << wklog) + (kg << 1); byte ^= (ns & 7) << 4;
            bf16x8 b = *(const bf16x8*)(W + byte);
            acc[g][0] = MFMA_BF16(a0, b, acc[g][0]);
            acc[g][1] = MFMA_BF16(a1, b, acc[g][1]);
        }
    }
}
// A-chunked GEMM phase: depth-2 reg prefetch, double-buffered LDS. nch even (4 or 8).
__device__ __forceinline__ void run_phase(int nch, const u16* s0, const u16* s1,
    char* A0, char* A1, const char* W, int wklog, int M0, int tid, int wv, int lane,
    f32x4 acc[4][2])
{
    Regs4 R0, R1;
    load_A(R0, abase(s0, s1, 0), M0, tid);
    load_A(R1, abase(s0, s1, 1), M0, tid);
    write_A(A0, R0, tid);
    __syncthreads();
    for (int c = 0; c < nch; c += 2) {
        if (c + 2 < nch) load_A(R0, abase(s0, s1, c + 2), M0, tid);
        compute_chunk(A0, W, wklog, c * 64, wv, lane, acc);
        write_A(A1, R1, tid);
        __syncthreads();
        if (c + 3 < nch) load_A(R1, abase(s0, s1, c + 3), M0, tid);
        compute_chunk(A1, W, wklog, (c + 1) * 64, wv, lane, acc);
        if (c + 2 < nch) write_A(A0, R0, tid);
        __syncthreads();
    }
}

// ---------------- persistent sequential kernel ----------------
// 256 WGs x 256 thr; 16 independent groups of 16 WGs (one M-tile of 128 batch rows each).
// LDS (dynamic 128KB): Whh0 slice 32K | W1 slice 64K | A dbuf 2x16K.
__global__ void __launch_bounds__(256, 1)
lstm_seq(const _Float16* __restrict__ xp,
         const u16* __restrict__ Wh0f, const u16* __restrict__ Wh0r,
         const u16* __restrict__ W1f,  const u16* __restrict__ W1r,
         const float* __restrict__ bs1f, const float* __restrict__ bs1r,
         u16* __restrict__ h0f, u16* __restrict__ h1f,
         u16* __restrict__ h0r, u16* __restrict__ h1r,
         float* __restrict__ latent, unsigned* __restrict__ ctl)
{
    extern __shared__ char lds[];
    char* Wh0s = lds;            // 32768: 64 rows x 256 k bf16, swizzled
    char* W1s  = lds + 32768;    // 65536: 64 rows x 512 k
    char* A0   = lds + 98304;    // 16384: 128 x 64 bf16
    char* A1   = lds + 114688;   // 16384

    const int tid = threadIdx.x, wv = tid >> 6, lane = tid & 63;
    const int bid = blockIdx.x;
    const int xcd = bid & 7, j = bid >> 3;
    const int grp = xcd * 2 + (j >> 4);   // 0..15; members co-XCD by dispatch heuristic
    const int mem = j & 15;
    const int M0  = grp * 128;
    const int HC0 = mem * 16;
    const int hc  = HC0 + (lane & 15);
    unsigned* bar = ctl + grp * 64;       // 256 B per group

    for (int dir = 0; dir < 2; ++dir) {
        const int nst = dir ? RSTEPS : FSTEPS;
        const u16* Wh0g = dir ? Wh0r : Wh0f;
        const u16* W1g  = dir ? W1r  : W1f;
        const float* bs1 = dir ? bs1r : bs1f;
        u16* h0 = dir ? h0r : h0f;
        u16* h1 = dir ? h1r : h1f;

        // ---- load weight slices into LDS (once per direction) ----
#pragma unroll
        for (int i = 0; i < 8; ++i) {            // Whh0: 64 rows x 256
            int u = tid + i * 256;
            int ns = u >> 5, k8 = (u & 31) << 3;
            int n = ((ns >> 4) << 8) + HC0 + (ns & 15);
            u16x8 v = *(const u16x8*)(Wh0g + (size_t)n * 256 + k8);
            int byte = (ns << 9) + (k8 << 1); byte ^= (ns & 7) << 4;
            *(u16x8*)(Wh0s + byte) = v;
        }
#pragma unroll
        for (int i = 0; i < 16; ++i) {           // W1: 64 rows x 512
            int u = tid + i * 256;
            int ns = u >> 6, k8 = (u & 63) << 3;
            int n = ((ns >> 4) << 8) + HC0 + (ns & 15);
            u16x8 v = *(const u16x8*)(W1g + (size_t)n * 512 + k8);
            int byte = (ns << 10) + (k8 << 1); byte ^= (ns & 7) << 4;
            *(u16x8*)(W1s + byte) = v;
        }
        __syncthreads();

        float b1reg[4];
#pragma unroll
        for (int g = 0; g < 4; ++g) b1reg[g] = bs1[g * 256 + hc];

        float c0[2][4], c1[2][4];                // cell state in registers
#pragma unroll
        for (int m = 0; m < 2; ++m)
#pragma unroll
            for (int r = 0; r < 4; ++r) { c0[m][r] = 0.f; c1[m][r] = 0.f; }

        for (int t = 0; t < nst; ++t) {
            u16* h0prev = h0 + ((t + 1) & 1) * SZH;
            u16* h0cur  = h0 + (t & 1) * SZH;
            u16* h1prev = h1 + ((t + 1) & 1) * SZH;
            u16* h1cur  = h1 + (t & 1) * SZH;

            // ======== layer0: gates = xproj[t] + h0prev @ Whh0^T ========
            const int vf = dir ? (32 + t) : t;
            const _Float16* xpb = xp + ((size_t)vf * 2048 + M0) * 1024;
            float xq[4][2][4];
#pragma unroll
            for (int g = 0; g < 4; ++g)
#pragma unroll
                for (int m = 0; m < 2; ++m)
#pragma unroll
                    for (int r = 0; r < 4; ++r) {
                        int rowin = wv * 32 + m * 16 + ((lane >> 4) << 2) + r;
                        xq[g][m][r] = (float)xpb[(size_t)rowin * 1024 + g * 256 + hc];
                    }

            f32x4 acc[4][2];
#pragma unroll
            for (int g = 0; g < 4; ++g) { acc[g][0] = (f32x4){0.f,0.f,0.f,0.f}; acc[g][1] = (f32x4){0.f,0.f,0.f,0.f}; }
            run_phase(4, h0prev, h0prev, A0, A1, Wh0s, 9, M0, tid, wv, lane, acc);
#pragma unroll
            for (int m = 0; m < 2; ++m)
#pragma unroll
                for (int r = 0; r < 4; ++r) {
                    int row = M0 + wv * 32 + m * 16 + ((lane >> 4) << 2) + r;
                    float gi = acc[0][m][r] + xq[0][m][r];
                    float gf = acc[1][m][r] + xq[1][m][r];
                    float gg = acc[2][m][r] + xq[2][m][r];
                    float go = acc[3][m][r] + xq[3][m][r];
                    float cn = sigm(gf) * c0[m][r] + sigm(gi) * tanh_fast(gg);
                    c0[m][r] = cn;
                    h0cur[(size_t)row * HID + hc] = f2bf(sigm(go) * tanh_fast(cn));
                }
            gbar16(bar);   // the only barrier per step (deps are group-local)

            // ======== layer1: gates = [h0cur | h1prev] @ W1^T + b1 ========
#pragma unroll
            for (int g = 0; g < 4; ++g) { acc[g][0] = (f32x4){0.f,0.f,0.f,0.f}; acc[g][1] = (f32x4){0.f,0.f,0.f,0.f}; }
            run_phase(8, h0cur, h1prev, A0, A1, W1s, 10, M0, tid, wv, lane, acc);
            const bool last = (t == nst - 1);
#pragma unroll
            for (int m = 0; m < 2; ++m)
#pragma unroll
                for (int r = 0; r < 4; ++r) {
                    int row = M0 + wv * 32 + m * 16 + ((lane >> 4) << 2) + r;
                    float gi = acc[0][m][r] + b1reg[0];
                    float gf = acc[1][m][r] + b1reg[1];
                    float gg = acc[2][m][r] + b1reg[2];
                    float go = acc[3][m][r] + b1reg[3];
                    float cn = sigm(gf) * c1[m][r] + sigm(gi) * tanh_fast(gg);
                    c1[m][r] = cn;
                    float hn = sigm(go) * tanh_fast(cn);
                    h1cur[(size_t)row * HID + hc] = f2bf(hn);
                    if (last) latent[(size_t)row * 512 + dir * 256 + hc] = hn;
                }
        }
    }
}

// ---------------- x-projection GEMM ----------------
// xp[vf][b][n] = xs[b][frame(vf)][:] @ Wih0_dir^T + (bih0+bhh0), fp16 out.
// 128x128 tile, K=512; grid 560 Mtiles x 8 Ntiles, XCD-chunked so one XCD reuses an A-tile 8x.
__global__ void __launch_bounds__(256)
xproj_gemm(const float* __restrict__ xs,
           const u16* __restrict__ W0xf, const u16* __restrict__ W0xr,
           const float* __restrict__ bs0f, const float* __restrict__ bs0r,
           _Float16* __restrict__ xp)
{
    __shared__ char As[16384];
    __shared__ char Bs[16384];
    const int tid = threadIdx.x, wv = tid >> 6, lane = tid & 63;
    const int phys = blockIdx.x;
    const int xcd = phys & 7, idx = phys >> 3;
    const int mt = xcd * 70 + (idx >> 3);     // 0..559
    const int nt = idx & 7;
    const int vf = mt >> 4;
    const int dirr = (vf >= 32);
    const int frame = dirr ? (95 - vf) : (30 + vf);
    const int brow = (mt & 15) * 128;
    const u16* Wp = (dirr ? W0xr : W0xf) + (size_t)nt * 128 * 512;
    const float* bs = dirr ? bs0r : bs0f;

    float breg[8];
#pragma unroll
    for (int n = 0; n < 8; ++n) breg[n] = bs[nt * 128 + n * 16 + (lane & 15)];

    f32x4 acc[8][2];
#pragma unroll
    for (int n = 0; n < 8; ++n) { acc[n][0] = (f32x4){0.f,0.f,0.f,0.f}; acc[n][1] = (f32x4){0.f,0.f,0.f,0.f}; }

    const int ar = tid >> 1, akoff = (tid & 1) * 32;
    const float* asrc0 = xs + ((size_t)(brow + ar) * 64 + frame) * 512 + akoff;

    for (int c = 0; c < 8; ++c) {
        {   // stage A: 128 rows x 64 k, fp32 -> bf16
            const float* s = asrc0 + c * 64;
            u16x8 o[4];
#pragma unroll
            for (int j2 = 0; j2 < 4; ++j2) {
                float4 f0 = *(const float4*)(s + j2 * 8);
                float4 f1 = *(const float4*)(s + j2 * 8 + 4);
                u16x8 o_;
                o_[0] = f2bf(f0.x); o_[1] = f2bf(f0.y); o_[2] = f2bf(f0.z); o_[3] = f2bf(f0.w);
                o_[4] = f2bf(f1.x); o_[5] = f2bf(f1.y); o_[6] = f2bf(f1.z); o_[7] = f2bf(f1.w);
                o[j2] = o_;
            }
#pragma unroll
            for (int j2 = 0; j2 < 4; ++j2) {
                int k = akoff + j2 * 8;
                int byte = (ar << 7) + (k << 1); byte ^= (ar & 7) << 4;
                *(u16x8*)(As + byte) = o[j2];
            }
        }
#pragma unroll
        for (int i = 0; i < 4; ++i) {   // stage B: 128 rows x 64 k
            int u = tid + i * 256;
            int ns = u >> 3, c8 = (u & 7) << 3;
            u16x8 v = *(const u16x8*)(Wp + (size_t)ns * 512 + c * 64 + c8);
            int byte = (ns << 7) + (c8 << 1); byte ^= (ns & 7) << 4;
            *(u16x8*)(Bs + byte) = v;
        }
        __syncthreads();
#pragma unroll
        for (int kk = 0; kk < 2; ++kk) {
            int kin = kk * 32 + (lane >> 4) * 8;
            bf16x8 a0, a1;
            int row = wv * 32 + (lane & 15);
            int byte = (row << 7) + (kin << 1); byte ^= (row & 7) << 4;
            a0 = *(const bf16x8*)(As + byte);
            int row1 = row + 16;
            byte = (row1 << 7) + (kin << 1); byte ^= (row1 & 7) << 4;
            a1 = *(const bf16x8*)(As + byte);
#pragma unroll
            for (int n = 0; n < 8; ++n) {
                int ns = n * 16 + (lane & 15);
                int bb = (ns << 7) + (kin << 1); bb ^= (ns & 7) << 4;
                bf16x8 bf_ = *(const bf16x8*)(Bs + bb);
                acc[n][0] = MFMA_BF16(a0, bf_, acc[n][0]);
                acc[n][1] = MFMA_BF16(a1, bf_, acc[n][1]);
            }
        }
        __syncthreads();
    }
#pragma unroll
    for (int n = 0; n < 8; ++n)
#pragma unroll
        for (int m = 0; m < 2; ++m)
#pragma unroll
            for (int r = 0; r < 4; ++r) {
                int vm = mt * 128 + wv * 32 + m * 16 + ((lane >> 4) << 2) + r;
                int col = nt * 128 + n * 16 + (lane & 15);
                xp[(size_t)vm * 1024 + col] = (_Float16)(acc[n][m][r] + breg[n]);
            }
}

// ---------------- prep: pack [Wa|Wb] rows -> bf16; bias sum ----------------
__global__ void pack_w(const float* __restrict__ Wa, int da,
                       const float* __restrict__ Wb, int db,
                       const float* __restrict__ bi, const float* __restrict__ bh,
                       u16* __restrict__ Wout, float* __restrict__ bout)
{
    int K = da + db;
    int total = 1024 * K;
    int gt = blockIdx.x * blockDim.x + threadIdx.x;
    int stride = gridDim.x * blockDim.x;
    for (int i = gt; i < total; i += stride) {
        int n = i / K, k = i - n * K;
        float v = (k < da) ? Wa[(size_t)n * da + k] : Wb[(size_t)n * db + (k - da)];
        Wout[i] = f2bf(v);
    }
    if (bout && gt < 1024) bout[gt] = bi[gt] + bh[gt];
}

// ---------------- final linear ----------------
__global__ void final_linear(const float* __restrict__ latent, const float* __restrict__ W3,
                             const float* __restrict__ b3, float* __restrict__ out)
{
    int idx = blockIdx.x * blockDim.x + threadIdx.x;
    if (idx >= BATCH * 10) return;
    int bb = idx / 10, c = idx - bb * 10;
    const float* lrow = latent + (size_t)bb * 512;
    const float* wrow = W3 + (size_t)c * 512;
    float s = b3[c];
#pragma unroll 4
    for (int k = 0; k < 512; k += 4) {
        float4 lv = *(const float4*)(lrow + k);
        float4 wv = *(const float4*)(wrow + k);
        s += lv.x * wv.x + lv.y * wv.y + lv.z * wv.z + lv.w * wv.w;
    }
    out[idx] = s;
}

// ---------------- launch ----------------
extern "C" void kernel_launch(void* const* d_in, const int* in_sizes, int n_in,
                              void* d_out, int out_size, void* d_ws, size_t ws_size,
                              hipStream_t stream)
{
    (void)in_sizes; (void)n_in; (void)out_size;
    if (ws_size < WS_NEED) return;   // leaves d_out poisoned -> diagnosable as ws shortfall

    const float* xs     = (const float*)d_in[0];
    const float* Wih_f0 = (const float*)d_in[1];
    const float* Whh_f0 = (const float*)d_in[2];
    const float* bih_f0 = (const float*)d_in[3];
    const float* bhh_f0 = (const float*)d_in[4];
    const float* Wih_f1 = (const float*)d_in[5];
    const float* Whh_f1 = (const float*)d_in[6];
    const float* bih_f1 = (const float*)d_in[7];
    const float* bhh_f1 = (const float*)d_in[8];
    const float* Wih_r0 = (const float*)d_in[9];
    const float* Whh_r0 = (const float*)d_in[10];
    const float* bih_r0 = (const float*)d_in[11];
    const float* bhh_r0 = (const float*)d_in[12];
    const float* Wih_r1 = (const float*)d_in[13];
    const float* Whh_r1 = (const float*)d_in[14];
    const float* bih_r1 = (const float*)d_in[15];
    const float* bhh_r1 = (const float*)d_in[16];
    const float* W3     = (const float*)d_in[17];
    const float* b3     = (const float*)d_in[18];

    char* ws = (char*)d_ws;
    unsigned* ctl = (unsigned*)(ws + OFF_CTL);
    u16* h0f = (u16*)(ws + OFF_H0F);
    u16* h1f = (u16*)(ws + OFF_H1F);
    u16* h0r = (u16*)(ws + OFF_H0R);
    u16* h1r = (u16*)(ws + OFF_H1R);
    float* latent = (float*)(ws + OFF_LAT);
    _Float16* xp = (_Float16*)(ws + OFF_XP);
    u16* W0xf = (u16*)(ws + OFF_W0XF);
    u16* W0xr = (u16*)(ws + OFF_W0XR);
    u16* Wh0f = (u16*)(ws + OFF_WH0F);
    u16* Wh0r = (u16*)(ws + OFF_WH0R);
    u16* W1f  = (u16*)(ws + OFF_W1F);
    u16* W1r  = (u16*)(ws + OFF_W1R);
    float* bs0f = (float*)(ws + OFF_BS0F);
    float* bs0r = (float*)(ws + OFF_BS0R);
    float* bs1f = (float*)(ws + OFF_BS1F);
    float* bs1r = (float*)(ws + OFF_BS1R);

    hipMemsetAsync(d_ws, 0, ZERO_BYTES, stream);   // ctl + h buffers

    pack_w<<<256, 256, 0, stream>>>(Wih_f0, 512, Wih_f0, 0, bih_f0, bhh_f0, W0xf, bs0f);
    pack_w<<<256, 256, 0, stream>>>(Whh_f0, 256, Whh_f0, 0, nullptr, nullptr, Wh0f, nullptr);
    pack_w<<<256, 256, 0, stream>>>(Wih_f1, 256, Whh_f1, 256, bih_f1, bhh_f1, W1f, bs1f);
    pack_w<<<256, 256, 0, stream>>>(Wih_r0, 512, Wih_r0, 0, bih_r0, bhh_r0, W0xr, bs0r);
    pack_w<<<256, 256, 0, stream>>>(Whh_r0, 256, Whh_r0, 0, nullptr, nullptr, Wh0r, nullptr);
    pack_w<<<256, 256, 0, stream>>>(Wih_r1, 256, Whh_r1, 256, bih_r1, bhh_r1, W1r, bs1r);

    xproj_gemm<<<4480, 256, 0, stream>>>(xs, W0xf, W0xr, bs0f, bs0r, xp);

    hipFuncSetAttribute((const void*)lstm_seq,
                        hipFuncAttributeMaxDynamicSharedMemorySize, 131072);
    lstm_seq<<<256, 256, 131072, stream>>>(xp, Wh0f, Wh0r, W1f, W1r, bs1f, bs1r,
                                           h0f, h1f, h0r, h1r, latent, ctl);

    final_linear<<<80, 256, 0, stream>>>(latent, W3, b3, (float*)d_out);
}